// Round 4
// baseline (139.809 us; speedup 1.0000x reference)
//
#include <hip/hip_runtime.h>
#include <hip/hip_bf16.h>
#include <math.h>

// B=8, T=2048, C=1024, H=64 causal single-head attention, scale 1/32.
// wt2 (W -> B-frag order) -> qkv v5 (16-row tiles, B direct-to-reg from
// fragment-ordered Wt2, x via 4-deep reg prefetch + tiny LDS dbuf, lgkm-only
// barriers, 4 blocks/CU) -> attn_part (4-wave shared-KV flash) -> combine.

#define BT 16384
#define TSEQ 2048
#define XST 72   // LDS row stride (ushorts)

typedef __attribute__((ext_vector_type(8))) __bf16 bf16x8;
typedef __attribute__((ext_vector_type(8))) unsigned short ushort8;
typedef __attribute__((ext_vector_type(4))) float floatx4;

#define MFMA16(a, b, c) __builtin_amdgcn_mfma_f32_16x16x32_bf16( \
    __builtin_bit_cast(bf16x8, (a)), __builtin_bit_cast(bf16x8, (b)), (c), 0, 0, 0)

__device__ inline unsigned short f2bf(float f) {
  unsigned u = __builtin_bit_cast(unsigned, f);
  u += 0x7FFFu + ((u >> 16) & 1u);   // RNE
  return (unsigned short)(u >> 16);
}
__device__ inline float bf2f(unsigned short s) {
  return __builtin_bit_cast(float, (unsigned)s << 16);
}
__device__ inline unsigned long long pack4bf(floatx4 f) {
  return (unsigned long long)f2bf(f[0]) | ((unsigned long long)f2bf(f[1]) << 16) |
         ((unsigned long long)f2bf(f[2]) << 32) | ((unsigned long long)f2bf(f[3]) << 48);
}
__device__ inline void glds16(const unsigned short* g, unsigned short* l) {
  __builtin_amdgcn_global_load_lds(
      (const __attribute__((address_space(1))) unsigned int*)g,
      (__attribute__((address_space(3))) unsigned int*)l, 16, 0, 0);
}

// ---------------------------------------------------------------------------
// Kernel 0: Wt2 in MFMA B-fragment order, coalesced both ways via LDS bounce.
// flat u16 = ((nt*16 + kci)*2 + half)*512 + lane*8 ; elem j = W[c][h],
// c = kci*64 + half*32 + quad*8 + j, h = (nt&3)*16 + l16, mat = nt>>2.
// ---------------------------------------------------------------------------
__global__ __launch_bounds__(256) void wt2_kernel(
    const float* __restrict__ Wq, const float* __restrict__ Wk,
    const float* __restrict__ Wv, unsigned short* __restrict__ Wt2) {
  __shared__ float ls[64][65];
  const int m = blockIdx.x >> 4;
  const int kci = blockIdx.x & 15;
  const int c0 = kci << 6;
  const float* __restrict__ W = (m == 0) ? Wq : (m == 1) ? Wk : Wv;
  const int tid = threadIdx.x;
#pragma unroll
  for (int i = 0; i < 16; ++i) {
    int idx = tid + (i << 8);
    int cl = idx >> 6, h = idx & 63;
    ls[cl][h] = W[(c0 + cl) * 64 + h];
  }
  __syncthreads();
  const int w = tid >> 6, lane = tid & 63;
  const int quad = lane >> 4, l16 = lane & 15;
  const int nt = (m << 2) + w;
#pragma unroll
  for (int half = 0; half < 2; ++half) {
    ushort8 t;
#pragma unroll
    for (int j = 0; j < 8; ++j)
      t[j] = f2bf(ls[(half << 5) + (quad << 3) + j][(w << 4) + l16]);
    *(ushort8*)(Wt2 + ((size_t)(((nt << 4) + kci) * 2 + half) << 9) +
                (lane << 3)) = t;
  }
}

// ---------------------------------------------------------------------------
// Kernel 1 (v5): 16-row M-tile, grid 1024 x 256 thr (4 waves), 4 blocks/CU.
// Wave w owns nt {3w..3w+2} for all 16 rows (acc[3], no split-K reduce).
// B: direct global->reg dwordx4 from fragment-ordered Wt2, double-buffered;
// compiler-precise vmcnt waits only (no counted drains, no glds).
// x: 4-deep reg prefetch (slack ~3 iters) -> pack4bf -> tiny LDS dbuf
// [16][72]; barriers are lgkmcnt(0)-only so x loads NEVER drain at barriers.
// LDS 7.5 KB; ~110 VGPR -> 16 waves/CU of desynced TLP.
// ---------------------------------------------------------------------------
#define XB16 1152    // u16: one x buffer [16][72]

__global__ __launch_bounds__(256, 4) void qkv_mfma(
    const float* __restrict__ x, const unsigned short* __restrict__ Wt2,
    unsigned short* __restrict__ Qf, unsigned short* __restrict__ Kf,
    unsigned short* __restrict__ Vf) {
  __shared__ __align__(16) unsigned short smem[3840];  // loop 2*1152; epi 3840

  const int tid = threadIdx.x;
  const int w = tid >> 6, lane = tid & 63;
  const int quad = lane >> 4, l16 = lane & 15;
  const int r0 = blockIdx.x << 4;
  const int xrow = tid >> 4;           // 0..15
  const int xcol = (tid & 15) << 2;    // 0,4,..60
  const float* __restrict__ xp = x + (size_t)(r0 + xrow) * 1024 + xcol;
  const int xw = xrow * XST + xcol;
  const unsigned short* __restrict__ bbase = Wt2 + (lane << 3);

  floatx4 acc[3];
#pragma unroll
  for (int n = 0; n < 3; ++n) acc[n] = (floatx4){0.f, 0.f, 0.f, 0.f};

  // ---- prologue: x(0..3) to regs, B(0) to regs, stage xb[0] ----
  floatx4 pf[4];
#pragma unroll
  for (int s = 0; s < 4; ++s) pf[s] = *(const floatx4*)(xp + (s << 6));
  ushort8 bfr[2][3][2];
#pragma unroll
  for (int n = 0; n < 3; ++n)
#pragma unroll
    for (int h = 0; h < 2; ++h)
      bfr[0][n][h] = *(const ushort8*)(bbase +
          ((size_t)(((3 * w + n) << 5) + h) << 9));
  *(unsigned long long*)&smem[xw] = pack4bf(pf[0]);
  asm volatile("s_waitcnt lgkmcnt(0)" ::: "memory");
  __builtin_amdgcn_sched_barrier(0);
  __builtin_amdgcn_s_barrier();
  __builtin_amdgcn_sched_barrier(0);

#pragma unroll
  for (int c = 0; c < 16; ++c) {
    const int cur = c & 1;
    // stage x(c+1) (consumes pf[(c+1)&3], loaded 3 iters ago)
    if (c + 1 < 16)
      *(unsigned long long*)&smem[((c + 1) & 1) * XB16 + xw] =
          pack4bf(pf[(c + 1) & 3]);
    // refill pf with x(c+4)
    if (c + 4 < 16) pf[c & 3] = *(const floatx4*)(xp + ((c + 4) << 6));
    // B(c+1) -> regs (wave-private; compiler inserts precise vmcnt)
    if (c + 1 < 16) {
#pragma unroll
      for (int n = 0; n < 3; ++n)
#pragma unroll
        for (int h = 0; h < 2; ++h)
          bfr[(c + 1) & 1][n][h] = *(const ushort8*)(bbase +
              ((size_t)((((3 * w + n) << 4) + (c + 1)) * 2 + h) << 9));
    }
    // compute chunk c
    ushort8 af[2];
#pragma unroll
    for (int h = 0; h < 2; ++h)
      af[h] = *(const ushort8*)&smem[cur * XB16 + l16 * XST + (h << 5) +
                                     (quad << 3)];
#pragma unroll
    for (int h = 0; h < 2; ++h)
#pragma unroll
      for (int n = 0; n < 3; ++n)
        acc[n] = MFMA16(af[h], bfr[cur][n][h], acc[n]);

    // lgkm-only barrier: x/B global loads stay in flight across it
    asm volatile("s_waitcnt lgkmcnt(0)" ::: "memory");
    __builtin_amdgcn_sched_barrier(0);
    __builtin_amdgcn_s_barrier();
    __builtin_amdgcn_sched_barrier(0);
  }

  // ---- epilogue: stage Q/K row-major, V transposed; then emit frags ----
  // regions: qs = smem[0..1152), ks = [1152..2304), vt[64][24] = [2304..3840)
#pragma unroll
  for (int i = 0; i < 3; ++i) {
    const int nt = 3 * w + i;
    const int m = nt >> 2, hg = nt & 3;
    if (m < 2) {
#pragma unroll
      for (int r = 0; r < 4; ++r)
        smem[m * XB16 + ((quad << 2) + r) * XST + (hg << 4) + l16] =
            f2bf(acc[i][r]);
    } else {
      *(unsigned long long*)&smem[2304 + ((hg << 4) + l16) * 24 + (quad << 2)] =
          pack4bf(acc[i]);
    }
  }
  __syncthreads();

  const int b = r0 >> 11;
  const int r16 = (r0 & 2047) >> 4;
  const int st = (r0 & 2047) >> 6;
  const int ntK = (r0 >> 4) & 3;
  const int khV = (r0 >> 5) & 1;
  const int q0v = (r0 >> 3) & 3;   // 0 or 2
#pragma unroll
  for (int i = 0; i < 2; ++i) {
    const int f = (w << 1) + i;
    if (f < 2) {
      const int kh = f;
      ushort8 t = *(const ushort8*)&smem[l16 * XST + (kh << 5) + (quad << 3)];
      *(ushort8*)(Qf + ((((size_t)b * 128 + r16) * 2 + kh) << 9) +
                  (lane << 3)) = t;
    } else if (f < 4) {
      const int kh = f - 2;
      ushort8 t = *(const ushort8*)&smem[XB16 + l16 * XST + (kh << 5) +
                                         (quad << 3)];
      *(ushort8*)(Kf + ((((size_t)(b * 32 + st) * 4 + ntK) * 2 + kh) << 9) +
                  (lane << 3)) = t;
    } else {
      const int ntE = f - 4;
      if ((quad >> 1) == (q0v >> 1)) {
        ushort8 t = *(const ushort8*)&smem[2304 + ((ntE << 4) + l16) * 24 +
                                           ((quad - q0v) << 3)];
        *(ushort8*)(Vf + ((((size_t)(b * 32 + st) * 4 + ntE) * 2 + khV) << 9) +
                    (lane << 3)) = t;
      }
    }
  }
}

// ---------------------------------------------------------------------------
// Kernel 2: split-K flash attention, 4-wave blocks sharing K/V via LDS.
// Grid 8 x 144 = 1152 blocks x 256 thr; block owns the full 64-row q-tile of
// one (b,e) unit; wave w = 16-row group. Per s-step: 16 KB K/V staged ONCE
// per block by global_load_lds (dbuf, counted vmcnt(4), 2 raw barriers/step).
// ---------------------------------------------------------------------------
__global__ __launch_bounds__(256, 3) void attn_part(
    const unsigned short* __restrict__ Qf, const unsigned short* __restrict__ Kf,
    const unsigned short* __restrict__ Vf, float* __restrict__ part) {
  __shared__ __align__(16) unsigned short KV[2][8192];   // 16 frag slots x 1KB
  __shared__ unsigned short Pw[4][16 * XST];

  const int tid = threadIdx.x;
  const int w = tid >> 6, lane = tid & 63;
  const int quad = lane >> 4, l16 = lane & 15;
  const int b = blockIdx.x / 144;
  const int e = blockIdx.x - b * 144;
  int g = 0;
#pragma unroll
  for (int gg = 1; gg < 8; ++gg) g += (e >= 2 * gg * (gg + 1)) ? 1 : 0;
  const int rem2 = e - 2 * g * (g + 1);
  const int qt = (g << 2) + rem2 / (g + 1);
  const int ch = rem2 - (rem2 / (g + 1)) * (g + 1);
  const int s0 = ch << 2;
  const int s1 = (s0 + 4 < qt + 1) ? s0 + 4 : qt + 1;
  const int r16 = (qt << 2) + w;

#define KVIDX(ss, nt, kh) \
  (((((size_t)(b * 32 + (ss)) << 2) + (nt)) * 2 + (kh)) << 9)
#define STAGE_KV(ss, db)                                                     \
  {                                                                          \
    _Pragma("unroll") for (int r_ = 0; r_ < 4; ++r_) {                       \
      const int f_ = (r_ << 2) + w;                                          \
      const unsigned short* src_ =                                           \
          (f_ < 8) ? Kf + KVIDX(ss, (f_ >> 1), (f_ & 1)) + (lane << 3)       \
                   : Vf + KVIDX(ss, (f_ >> 1) - 4, (f_ & 1)) + (lane << 3);  \
      glds16(src_, &KV[db][f_ << 9]);                                        \
    }                                                                        \
  }

  const unsigned short* qbase =
      Qf + ((((size_t)b * 128 + r16) * 2) << 9) + (lane << 3);
  ushort8 qf0 = *(const ushort8*)qbase;
  ushort8 qf1 = *(const ushort8*)(qbase + 512);
  __builtin_amdgcn_sched_barrier(0);

  STAGE_KV(s0, 0);
  __builtin_amdgcn_sched_barrier(0);
  STAGE_KV((s0 + 1 < s1) ? s0 + 1 : s1 - 1, 1);
  __builtin_amdgcn_sched_barrier(0);
  asm volatile("s_waitcnt vmcnt(4)");
  __builtin_amdgcn_sched_barrier(0);
  __builtin_amdgcn_s_barrier();
  __builtin_amdgcn_sched_barrier(0);

  floatx4 acc[4], lacc;
#pragma unroll
  for (int nt = 0; nt < 4; ++nt) acc[nt] = (floatx4){0.f, 0.f, 0.f, 0.f};
  lacc = (floatx4){0.f, 0.f, 0.f, 0.f};
  const ushort8 ones = {0x3F80, 0x3F80, 0x3F80, 0x3F80,
                        0x3F80, 0x3F80, 0x3F80, 0x3F80};

  for (int s = s0; s < s1; ++s) {
    const int cur = (s - s0) & 1;
    ushort8 bk[4][2], bv[4][2];
#pragma unroll
    for (int nt = 0; nt < 4; ++nt)
#pragma unroll
      for (int kh = 0; kh < 2; ++kh) {
        bk[nt][kh] = *(const ushort8*)&KV[cur][((((nt << 1) + kh)) << 9) +
                                              (lane << 3)];
        bv[nt][kh] = *(const ushort8*)&KV[cur][(((8 + (nt << 1) + kh)) << 9) +
                                              (lane << 3)];
      }
    asm volatile("s_waitcnt lgkmcnt(0)");
    __builtin_amdgcn_sched_barrier(0);
    __builtin_amdgcn_s_barrier();          // all waves done reading buf[cur]
    __builtin_amdgcn_sched_barrier(0);

    STAGE_KV((s + 2 < s1) ? s + 2 : s1 - 1, cur);
    __builtin_amdgcn_sched_barrier(0);

    floatx4 sf[4];
#pragma unroll
    for (int nt = 0; nt < 4; ++nt) {
      sf[nt] = (floatx4){0.f, 0.f, 0.f, 0.f};
      sf[nt] = MFMA16(qf0, bk[nt][0], sf[nt]);
      sf[nt] = MFMA16(qf1, bk[nt][1], sf[nt]);
    }

    const bool diag = (s == qt);
    const int qrow = (w << 4) + (quad << 2);
#pragma unroll
    for (int nt = 0; nt < 4; ++nt) {
      const int keyl = (nt << 4) + l16;
#pragma unroll
      for (int r = 0; r < 4; ++r) {
        float ev = __expf(sf[nt][r] * 0.03125f);
        if (diag && keyl > qrow + r) ev = 0.f;
        Pw[w][((quad << 2) + r) * XST + keyl] = f2bf(ev);
      }
    }

#pragma unroll
    for (int kh = 0; kh < 2; ++kh) {
      ushort8 pa = *(const ushort8*)&Pw[w][l16 * XST + (kh << 5) + (quad << 3)];
      lacc = MFMA16(pa, ones, lacc);
#pragma unroll
      for (int nt = 0; nt < 4; ++nt) acc[nt] = MFMA16(pa, bv[nt][kh], acc[nt]);
    }

    __builtin_amdgcn_sched_barrier(0);
    asm volatile("s_waitcnt vmcnt(4)");
    __builtin_amdgcn_sched_barrier(0);
    __builtin_amdgcn_s_barrier();
    __builtin_amdgcn_sched_barrier(0);
  }
#undef STAGE_KV
#undef KVIDX

  float* slot = part + (size_t)(b * 144 + e) * 2112;
  if (l16 == 0) {
#pragma unroll
    for (int r = 0; r < 4; ++r) slot[(w << 4) + (quad << 2) + r] = lacc[r];
  }
  unsigned short* op = (unsigned short*)(slot + 64);
#pragma unroll
  for (int nt = 0; nt < 4; ++nt)
#pragma unroll
    for (int r = 0; r < 4; ++r)
      op[((w << 4) + (quad << 2) + r) * 64 + (nt << 4) + l16] = f2bf(acc[nt][r]);
}

// ---------------------------------------------------------------------------
// Kernel 3: combine <=8 partials: out = (sum o_i)/(sum l_i). grid = 512
// (b, qt, row-half), 256 thr, 8 u16 per thread, fully coalesced.
// ---------------------------------------------------------------------------
__global__ __launch_bounds__(256) void attn_combine(
    const float* __restrict__ part, float* __restrict__ out) {
  const int rh = blockIdx.x & 1;
  const int bqt = blockIdx.x >> 1;
  const int b = bqt >> 5, qt = bqt & 31;
  const int tid = threadIdx.x;
  const int row = (rh << 5) + (tid >> 3);
  const int hseg = (tid & 7) << 3;
  const int g = qt >> 2;
  const int nch = g + 1;
  const int ebase = 2 * g * (g + 1) + (qt & 3) * (g + 1);

  float l = 0.f;
  float ov[8];
#pragma unroll
  for (int i = 0; i < 8; ++i) ov[i] = 0.f;
  for (int c = 0; c < nch; ++c) {
    const float* slot = part + (size_t)(b * 144 + ebase + c) * 2112;
    l += slot[row];
    ushort8 o0 = *(const ushort8*)((const unsigned short*)(slot + 64) +
                                   row * 64 + hseg);
#pragma unroll
    for (int i = 0; i < 8; ++i) ov[i] += bf2f(o0[i]);
  }
  const float inv = 1.f / l;
  float* o = out + ((size_t)(b * TSEQ + (qt << 6) + row)) * 64 + hseg;
#pragma unroll
  for (int i = 0; i < 8; ++i) o[i] = ov[i] * inv;
}

extern "C" void kernel_launch(void* const* d_in, const int* in_sizes, int n_in,
                              void* d_out, int out_size, void* d_ws, size_t ws_size,
                              hipStream_t stream) {
  const float* x  = (const float*)d_in[0];
  const float* Wk = (const float*)d_in[1];
  const float* Wq = (const float*)d_in[2];
  const float* Wv = (const float*)d_in[3];

  unsigned short* Qfw = (unsigned short*)d_ws;          // 2 MB
  unsigned short* Kfw = Qfw + (size_t)BT * 64;          // 2 MB
  unsigned short* Vfw = Kfw + (size_t)BT * 64;          // 2 MB
  unsigned short* Wt2 = Vfw + (size_t)BT * 64;          // 384 KB
  float* part = (float*)(Wt2 + 3 * 64 * 1024);          // 1152*8448 B = 9.7 MB

  wt2_kernel<<<48, 256, 0, stream>>>(Wq, Wk, Wv, Wt2);
  qkv_mfma<<<1024, 256, 0, stream>>>(x, Wt2, Qfw, Kfw, Vfw);
  attn_part<<<1152, 256, 0, stream>>>(Qfw, Kfw, Vfw, part);
  attn_combine<<<512, 256, 0, stream>>>(part, (float*)d_out);
}

// Round 5
// 128.839 us; speedup vs baseline: 1.0851x; 1.0851x over previous
//
#include <hip/hip_runtime.h>
#include <hip/hip_bf16.h>
#include <math.h>

// B=8, T=2048, C=1024, H=64 causal single-head attention, scale 1/32.
// wt2 (W -> B-frag order) -> qkv v6 (64-row blocks, B via glds 3-deep,
// x via 4-deep reg prefetch; issue order B-before-x so counted vmcnt never
// drains young HBM loads) -> attn_part (4-wave shared-KV flash) -> combine.

#define BT 16384
#define TSEQ 2048
#define XST 72   // LDS row stride (ushorts)

typedef __attribute__((ext_vector_type(8))) __bf16 bf16x8;
typedef __attribute__((ext_vector_type(8))) unsigned short ushort8;
typedef __attribute__((ext_vector_type(4))) float floatx4;

#define MFMA16(a, b, c) __builtin_amdgcn_mfma_f32_16x16x32_bf16( \
    __builtin_bit_cast(bf16x8, (a)), __builtin_bit_cast(bf16x8, (b)), (c), 0, 0, 0)

__device__ inline unsigned short f2bf(float f) {
  unsigned u = __builtin_bit_cast(unsigned, f);
  u += 0x7FFFu + ((u >> 16) & 1u);   // RNE
  return (unsigned short)(u >> 16);
}
__device__ inline float bf2f(unsigned short s) {
  return __builtin_bit_cast(float, (unsigned)s << 16);
}
__device__ inline unsigned long long pack4bf(floatx4 f) {
  return (unsigned long long)f2bf(f[0]) | ((unsigned long long)f2bf(f[1]) << 16) |
         ((unsigned long long)f2bf(f[2]) << 32) | ((unsigned long long)f2bf(f[3]) << 48);
}
__device__ inline ushort8 pack8bf(floatx4 a, floatx4 b) {
  ushort8 t;
#pragma unroll
  for (int i = 0; i < 4; ++i) t[i] = f2bf(a[i]);
#pragma unroll
  for (int i = 0; i < 4; ++i) t[4 + i] = f2bf(b[i]);
  return t;
}
__device__ inline void glds16(const unsigned short* g, unsigned short* l) {
  __builtin_amdgcn_global_load_lds(
      (const __attribute__((address_space(1))) unsigned int*)g,
      (__attribute__((address_space(3))) unsigned int*)l, 16, 0, 0);
}

// ---------------------------------------------------------------------------
// Kernel 0: Wt2 in MFMA B-fragment order, coalesced both ways via LDS bounce.
// ---------------------------------------------------------------------------
__global__ __launch_bounds__(256) void wt2_kernel(
    const float* __restrict__ Wq, const float* __restrict__ Wk,
    const float* __restrict__ Wv, unsigned short* __restrict__ Wt2) {
  __shared__ float ls[64][65];
  const int m = blockIdx.x >> 4;
  const int kci = blockIdx.x & 15;
  const int c0 = kci << 6;
  const float* __restrict__ W = (m == 0) ? Wq : (m == 1) ? Wk : Wv;
  const int tid = threadIdx.x;
#pragma unroll
  for (int i = 0; i < 16; ++i) {
    int idx = tid + (i << 8);
    int cl = idx >> 6, h = idx & 63;
    ls[cl][h] = W[(c0 + cl) * 64 + h];
  }
  __syncthreads();
  const int w = tid >> 6, lane = tid & 63;
  const int quad = lane >> 4, l16 = lane & 15;
  const int nt = (m << 2) + w;
#pragma unroll
  for (int half = 0; half < 2; ++half) {
    ushort8 t;
#pragma unroll
    for (int j = 0; j < 8; ++j)
      t[j] = f2bf(ls[(half << 5) + (quad << 3) + j][(w << 4) + l16]);
    *(ushort8*)(Wt2 + ((size_t)(((nt << 4) + kci) * 2 + half) << 9) +
                (lane << 3)) = t;
  }
}

// ---------------------------------------------------------------------------
// Kernel 1 (v6): 64-row M-tile, grid 256 (1 block/CU), 512 thr = 8 waves.
// Wave (wr,wn): rows wr*32..+31, nt {3wn..3wn+2}. B: glds 3-deep.
// x: 4-deep reg prefetch (x(c+4) issued iter c, staged iter c+3).
// Per-iter issue order: [ds_write x(c+1)] [glds B(c+2)] [load x(c+4)];
// barrier wait = counted vmcnt (7/5/3/0) draining only B(c+1).
// LDS: xb 2x[64][72] + Bb 3x[24][512] u16 = 92 KB.
// ---------------------------------------------------------------------------
#define XBS 4608     // one x buffer: [64][72]
#define BB0 9216     // B region base (= 2*XBS)
#define BBS 12288    // one B buffer: 24 frags x 512

__global__ __launch_bounds__(512) void qkv_mfma(
    const float* __restrict__ x, const unsigned short* __restrict__ Wt2,
    unsigned short* __restrict__ Qf, unsigned short* __restrict__ Kf,
    unsigned short* __restrict__ Vf) {
  __shared__ __align__(16) unsigned short smem[46080];

  const int tid = threadIdx.x;
  const int w = tid >> 6, lane = tid & 63;
  const int quad = lane >> 4, l16 = lane & 15;
  const int wr = w >> 2, wn = w & 3;
  const int r0 = blockIdx.x << 6;
  const int xrow = (w << 3) + (lane >> 3);
  const int xcol = (lane & 7) << 3;
  const float* __restrict__ xp = x + (size_t)(r0 + xrow) * 1024 + xcol;
  const int xw_u16 = xrow * XST + xcol;

  floatx4 acc[2][3];
#pragma unroll
  for (int rt = 0; rt < 2; ++rt)
#pragma unroll
    for (int n = 0; n < 3; ++n) acc[rt][n] = (floatx4){0.f, 0.f, 0.f, 0.f};

  floatx4 pf[4][2];

  // ---- prologue: B(0), x(0..3), B(1), stage xb[0] ----
#pragma unroll
  for (int i = 0; i < 3; ++i) {
    const int f = 3 * w + i;
    glds16(Wt2 + ((size_t)(((f >> 1) << 4) * 2 + (f & 1)) << 9) + (lane << 3),
           &smem[BB0 + (f << 9)]);
  }
  __builtin_amdgcn_sched_barrier(0);
#pragma unroll
  for (int s = 0; s < 4; ++s) {
    pf[s][0] = *(const floatx4*)(xp + (s << 6));
    pf[s][1] = *(const floatx4*)(xp + (s << 6) + 4);
  }
  __builtin_amdgcn_sched_barrier(0);
#pragma unroll
  for (int i = 0; i < 3; ++i) {
    const int f = 3 * w + i;
    glds16(Wt2 + ((size_t)((((f >> 1) << 4) + 1) * 2 + (f & 1)) << 9) +
               (lane << 3),
           &smem[BB0 + BBS + (f << 9)]);
  }
  __builtin_amdgcn_sched_barrier(0);
  *(ushort8*)&smem[xw_u16] = pack8bf(pf[0][0], pf[0][1]);
  __builtin_amdgcn_sched_barrier(0);
  asm volatile("s_waitcnt vmcnt(11)");   // B(0) done; x(1..3), B(1) in flight
  asm volatile("s_waitcnt lgkmcnt(0)");
  __builtin_amdgcn_sched_barrier(0);
  __builtin_amdgcn_s_barrier();
  __builtin_amdgcn_sched_barrier(0);

#pragma unroll
  for (int c = 0; c < 16; ++c) {
    // stage x(c+1) from pf (loaded 3 iters ago -> deep HBM slack here)
    if (c + 1 < 16)
      *(ushort8*)&smem[((c + 1) & 1) * XBS + xw_u16] =
          pack8bf(pf[(c + 1) & 3][0], pf[(c + 1) & 3][1]);
    __builtin_amdgcn_sched_barrier(0);
    // B(c+2) glds BEFORE this iter's x load (drain never forces young x)
    if (c + 2 < 16) {
#pragma unroll
      for (int i = 0; i < 3; ++i) {
        const int f = 3 * w + i;
        glds16(Wt2 + ((size_t)((((f >> 1) << 4) + (c + 2)) * 2 + (f & 1)) << 9) +
                   (lane << 3),
               &smem[BB0 + ((c + 2) % 3) * BBS + (f << 9)]);
      }
    }
    __builtin_amdgcn_sched_barrier(0);
    // refill pf with x(c+4)
    if (c + 4 < 16) {
      pf[c & 3][0] = *(const floatx4*)(xp + ((c + 4) << 6));
      pf[c & 3][1] = *(const floatx4*)(xp + ((c + 4) << 6) + 4);
    }
    __builtin_amdgcn_sched_barrier(0);

    // ---- compute chunk c from xb[c&1], Bb[c%3] ----
    ushort8 af[2][2];
#pragma unroll
    for (int rt = 0; rt < 2; ++rt)
#pragma unroll
      for (int h = 0; h < 2; ++h)
        af[rt][h] = *(const ushort8*)&smem[(c & 1) * XBS +
            ((wr << 5) + (rt << 4) + l16) * XST + (h << 5) + (quad << 3)];
    ushort8 bfr[3][2];
#pragma unroll
    for (int n = 0; n < 3; ++n)
#pragma unroll
      for (int h = 0; h < 2; ++h)
        bfr[n][h] = *(const ushort8*)&smem[BB0 + (c % 3) * BBS +
            ((((3 * wn + n) << 1) + h) << 9) + (lane << 3)];
#pragma unroll
    for (int h = 0; h < 2; ++h)
#pragma unroll
      for (int rt = 0; rt < 2; ++rt)
#pragma unroll
        for (int n = 0; n < 3; ++n)
          acc[rt][n] = MFMA16(af[rt][h], bfr[n][h], acc[rt][n]);

    __builtin_amdgcn_sched_barrier(0);
    // counted drain of B(c+1) only; in-flight kept: x(c+3),B(c+2),x(c+4)
    if (c <= 11)      { asm volatile("s_waitcnt vmcnt(7)"); }
    else if (c == 12) { asm volatile("s_waitcnt vmcnt(5)"); }
    else if (c == 13) { asm volatile("s_waitcnt vmcnt(3)"); }
    else              { asm volatile("s_waitcnt vmcnt(0)"); }
    asm volatile("s_waitcnt lgkmcnt(0)");
    __builtin_amdgcn_sched_barrier(0);
    __builtin_amdgcn_s_barrier();
    __builtin_amdgcn_sched_barrier(0);
  }

  // ---- epilogue: stage Q/K row-major, V transposed (reuse loop LDS) ----
#pragma unroll
  for (int n = 0; n < 3; ++n) {
    const int nt = 3 * wn + n;
    const int m = nt >> 2, hg = nt & 3;
#pragma unroll
    for (int rt = 0; rt < 2; ++rt) {
      const int rowb = (wr << 5) + (rt << 4) + (quad << 2);
      if (m < 2) {
#pragma unroll
        for (int r = 0; r < 4; ++r)
          smem[m * XBS + (rowb + r) * XST + (hg << 4) + l16] =
              f2bf(acc[rt][n][r]);
      } else {
        *(unsigned long long*)&smem[2 * XBS + ((hg << 4) + l16) * XST + rowb] =
            pack4bf(acc[rt][n]);
      }
    }
  }
  __syncthreads();

  // ---- emit fragment-packed Qf/Kf/Vf: 24 frags, 3 per wave, 1KB each ----
  const int b = blockIdx.x >> 5, st = blockIdx.x & 31;
#pragma unroll
  for (int i = 0; i < 3; ++i) {
    const int f = w * 3 + i;
    const int m = f >> 3, idx = f & 7, grp = idx >> 1, kh = idx & 1;
    ushort8 t = *(const ushort8*)&smem[m * XBS + ((grp << 4) + l16) * XST +
                                       (kh << 5) + (quad << 3)];
    unsigned short* dst;
    if (m == 0)
      dst = Qf + (((size_t)(b * 128 + (st << 2) + grp) * 2 + kh) << 9);
    else if (m == 1)
      dst = Kf + (((size_t)((b * 32 + st) * 4 + grp) * 2 + kh) << 9);
    else
      dst = Vf + (((size_t)((b * 32 + st) * 4 + grp) * 2 + kh) << 9);
    *(ushort8*)(dst + (lane << 3)) = t;
  }
}

// ---------------------------------------------------------------------------
// Kernel 2: split-K flash attention, 4-wave blocks sharing K/V via LDS.
// ---------------------------------------------------------------------------
__global__ __launch_bounds__(256, 3) void attn_part(
    const unsigned short* __restrict__ Qf, const unsigned short* __restrict__ Kf,
    const unsigned short* __restrict__ Vf, float* __restrict__ part) {
  __shared__ __align__(16) unsigned short KV[2][8192];   // 16 frag slots x 1KB
  __shared__ unsigned short Pw[4][16 * XST];

  const int tid = threadIdx.x;
  const int w = tid >> 6, lane = tid & 63;
  const int quad = lane >> 4, l16 = lane & 15;
  const int b = blockIdx.x / 144;
  const int e = blockIdx.x - b * 144;
  int g = 0;
#pragma unroll
  for (int gg = 1; gg < 8; ++gg) g += (e >= 2 * gg * (gg + 1)) ? 1 : 0;
  const int rem2 = e - 2 * g * (g + 1);
  const int qt = (g << 2) + rem2 / (g + 1);
  const int ch = rem2 - (rem2 / (g + 1)) * (g + 1);
  const int s0 = ch << 2;
  const int s1 = (s0 + 4 < qt + 1) ? s0 + 4 : qt + 1;
  const int r16 = (qt << 2) + w;

#define KVIDX(ss, nt, kh) \
  (((((size_t)(b * 32 + (ss)) << 2) + (nt)) * 2 + (kh)) << 9)
#define STAGE_KV(ss, db)                                                     \
  {                                                                          \
    _Pragma("unroll") for (int r_ = 0; r_ < 4; ++r_) {                       \
      const int f_ = (r_ << 2) + w;                                          \
      const unsigned short* src_ =                                           \
          (f_ < 8) ? Kf + KVIDX(ss, (f_ >> 1), (f_ & 1)) + (lane << 3)       \
                   : Vf + KVIDX(ss, (f_ >> 1) - 4, (f_ & 1)) + (lane << 3);  \
      glds16(src_, &KV[db][f_ << 9]);                                        \
    }                                                                        \
  }

  const unsigned short* qbase =
      Qf + ((((size_t)b * 128 + r16) * 2) << 9) + (lane << 3);
  ushort8 qf0 = *(const ushort8*)qbase;
  ushort8 qf1 = *(const ushort8*)(qbase + 512);
  __builtin_amdgcn_sched_barrier(0);

  STAGE_KV(s0, 0);
  __builtin_amdgcn_sched_barrier(0);
  STAGE_KV((s0 + 1 < s1) ? s0 + 1 : s1 - 1, 1);
  __builtin_amdgcn_sched_barrier(0);
  asm volatile("s_waitcnt vmcnt(4)");
  __builtin_amdgcn_sched_barrier(0);
  __builtin_amdgcn_s_barrier();
  __builtin_amdgcn_sched_barrier(0);

  floatx4 acc[4], lacc;
#pragma unroll
  for (int nt = 0; nt < 4; ++nt) acc[nt] = (floatx4){0.f, 0.f, 0.f, 0.f};
  lacc = (floatx4){0.f, 0.f, 0.f, 0.f};
  const ushort8 ones = {0x3F80, 0x3F80, 0x3F80, 0x3F80,
                        0x3F80, 0x3F80, 0x3F80, 0x3F80};

  for (int s = s0; s < s1; ++s) {
    const int cur = (s - s0) & 1;
    ushort8 bk[4][2], bv[4][2];
#pragma unroll
    for (int nt = 0; nt < 4; ++nt)
#pragma unroll
      for (int kh = 0; kh < 2; ++kh) {
        bk[nt][kh] = *(const ushort8*)&KV[cur][((((nt << 1) + kh)) << 9) +
                                              (lane << 3)];
        bv[nt][kh] = *(const ushort8*)&KV[cur][(((8 + (nt << 1) + kh)) << 9) +
                                              (lane << 3)];
      }
    asm volatile("s_waitcnt lgkmcnt(0)");
    __builtin_amdgcn_sched_barrier(0);
    __builtin_amdgcn_s_barrier();          // all waves done reading buf[cur]
    __builtin_amdgcn_sched_barrier(0);

    STAGE_KV((s + 2 < s1) ? s + 2 : s1 - 1, cur);
    __builtin_amdgcn_sched_barrier(0);

    floatx4 sf[4];
#pragma unroll
    for (int nt = 0; nt < 4; ++nt) {
      sf[nt] = (floatx4){0.f, 0.f, 0.f, 0.f};
      sf[nt] = MFMA16(qf0, bk[nt][0], sf[nt]);
      sf[nt] = MFMA16(qf1, bk[nt][1], sf[nt]);
    }

    const bool diag = (s == qt);
    const int qrow = (w << 4) + (quad << 2);
#pragma unroll
    for (int nt = 0; nt < 4; ++nt) {
      const int keyl = (nt << 4) + l16;
#pragma unroll
      for (int r = 0; r < 4; ++r) {
        float ev = __expf(sf[nt][r] * 0.03125f);
        if (diag && keyl > qrow + r) ev = 0.f;
        Pw[w][((quad << 2) + r) * XST + keyl] = f2bf(ev);
      }
    }

#pragma unroll
    for (int kh = 0; kh < 2; ++kh) {
      ushort8 pa = *(const ushort8*)&Pw[w][l16 * XST + (kh << 5) + (quad << 3)];
      lacc = MFMA16(pa, ones, lacc);
#pragma unroll
      for (int nt = 0; nt < 4; ++nt) acc[nt] = MFMA16(pa, bv[nt][kh], acc[nt]);
    }

    __builtin_amdgcn_sched_barrier(0);
    asm volatile("s_waitcnt vmcnt(4)");
    __builtin_amdgcn_sched_barrier(0);
    __builtin_amdgcn_s_barrier();
    __builtin_amdgcn_sched_barrier(0);
  }
#undef STAGE_KV
#undef KVIDX

  float* slot = part + (size_t)(b * 144 + e) * 2112;
  if (l16 == 0) {
#pragma unroll
    for (int r = 0; r < 4; ++r) slot[(w << 4) + (quad << 2) + r] = lacc[r];
  }
  unsigned short* op = (unsigned short*)(slot + 64);
#pragma unroll
  for (int nt = 0; nt < 4; ++nt)
#pragma unroll
    for (int r = 0; r < 4; ++r)
      op[((w << 4) + (quad << 2) + r) * 64 + (nt << 4) + l16] = f2bf(acc[nt][r]);
}

// ---------------------------------------------------------------------------
// Kernel 3: combine <=8 partials: out = (sum o_i)/(sum l_i).
// ---------------------------------------------------------------------------
__global__ __launch_bounds__(256) void attn_combine(
    const float* __restrict__ part, float* __restrict__ out) {
  const int rh = blockIdx.x & 1;
  const int bqt = blockIdx.x >> 1;
  const int b = bqt >> 5, qt = bqt & 31;
  const int tid = threadIdx.x;
  const int row = (rh << 5) + (tid >> 3);
  const int hseg = (tid & 7) << 3;
  const int g = qt >> 2;
  const int nch = g + 1;
  const int ebase = 2 * g * (g + 1) + (qt & 3) * (g + 1);

  float l = 0.f;
  float ov[8];
#pragma unroll
  for (int i = 0; i < 8; ++i) ov[i] = 0.f;
  for (int c = 0; c < nch; ++c) {
    const float* slot = part + (size_t)(b * 144 + ebase + c) * 2112;
    l += slot[row];
    ushort8 o0 = *(const ushort8*)((const unsigned short*)(slot + 64) +
                                   row * 64 + hseg);
#pragma unroll
    for (int i = 0; i < 8; ++i) ov[i] += bf2f(o0[i]);
  }
  const float inv = 1.f / l;
  float* o = out + ((size_t)(b * TSEQ + (qt << 6) + row)) * 64 + hseg;
#pragma unroll
  for (int i = 0; i < 8; ++i) o[i] = ov[i] * inv;
}

extern "C" void kernel_launch(void* const* d_in, const int* in_sizes, int n_in,
                              void* d_out, int out_size, void* d_ws, size_t ws_size,
                              hipStream_t stream) {
  const float* x  = (const float*)d_in[0];
  const float* Wk = (const float*)d_in[1];
  const float* Wq = (const float*)d_in[2];
  const float* Wv = (const float*)d_in[3];

  unsigned short* Qfw = (unsigned short*)d_ws;          // 2 MB
  unsigned short* Kfw = Qfw + (size_t)BT * 64;          // 2 MB
  unsigned short* Vfw = Kfw + (size_t)BT * 64;          // 2 MB
  unsigned short* Wt2 = Vfw + (size_t)BT * 64;          // 384 KB
  float* part = (float*)(Wt2 + 3 * 64 * 1024);          // 1152*8448 B = 9.7 MB

  wt2_kernel<<<48, 256, 0, stream>>>(Wq, Wk, Wv, Wt2);
  qkv_mfma<<<256, 512, 0, stream>>>(x, Wt2, Qfw, Kfw, Vfw);
  attn_part<<<1152, 256, 0, stream>>>(Qfw, Kfw, Vfw, part);
  attn_combine<<<512, 256, 0, stream>>>(part, (float*)d_out);
}